// Round 1
// baseline (182.210 us; speedup 1.0000x reference)
//
#include <hip/hip_runtime.h>
#include <hip/hip_bf16.h>
#include <cstdint>

#define NN 100000
#define DEG 16

// ---------- bf16 helpers ----------
__device__ __forceinline__ float bf2f(unsigned short u) {
    union { float f; uint32_t i; } c; c.i = ((uint32_t)u) << 16; return c.f;
}
__device__ __forceinline__ unsigned short f2bf(float f) {
    union { float f; uint32_t i; } c; c.f = f;
    uint32_t r = (c.i + 0x7FFFu + ((c.i >> 16) & 1u)) >> 16;
    return (unsigned short)r;
}

// ---------- kernel 1: per-node U = y@W1[0:64,:], V = y@W1[64:128,:]+b1, stored bf16 ----------
// UV layout: [node][256] bf16; cols 0..127 = U, cols 128..255 = V (+b1)
__global__ __launch_bounds__(256) void k_uv(
    const float* __restrict__ y, const float* __restrict__ W1,
    const float* __restrict__ b1, unsigned short* __restrict__ UV)
{
    __shared__ float wsh[128 * 128];   // full W1 (row-major 128x128)
    __shared__ float ysh[32][65];      // 32-node y tile, padded stride
    __shared__ float b1sh[128];

    const int t = threadIdx.x;
    const int tile = blockIdx.x;       // 3125 tiles x 32 nodes = 100000

    // stage W1 (64 KB)
    {
        const float4* src = (const float4*)W1;
        float4* dst = (float4*)wsh;
        #pragma unroll
        for (int i = 0; i < 16; ++i) dst[t + i * 256] = src[t + i * 256];
    }
    // stage y tile (32x64)
    {
        const int base = tile * 32 * 64;
        #pragma unroll
        for (int i = 0; i < 8; ++i) {
            int e = t + i * 256;
            ysh[e >> 6][e & 63] = y[base + e];
        }
    }
    if (t < 128) b1sh[t] = b1[t];
    __syncthreads();

    const int tx = t & 31;            // column group: 8 cols of 256
    const int ty = t >> 5;            // node group:   4 nodes of 32
    const int c0 = tx * 8;            // combined col 0..255
    const bool vhalf = (c0 >= 128);
    const int cc = vhalf ? (c0 - 128) : c0;   // col within W1 (0..127)
    const int rbase = vhalf ? 64 : 0;         // W1 row offset
    const int ty4 = ty * 4;

    float acc[4][8];
    #pragma unroll
    for (int g = 0; g < 4; ++g)
        #pragma unroll
        for (int c = 0; c < 8; ++c) acc[g][c] = 0.f;

    for (int k = 0; k < 64; ++k) {
        const float4 wa = *(const float4*)&wsh[(rbase + k) * 128 + cc];
        const float4 wb = *(const float4*)&wsh[(rbase + k) * 128 + cc + 4];
        const float w[8] = {wa.x, wa.y, wa.z, wa.w, wb.x, wb.y, wb.z, wb.w};
        #pragma unroll
        for (int g = 0; g < 4; ++g) {
            const float yv = ysh[ty4 + g][k];
            #pragma unroll
            for (int c = 0; c < 8; ++c)
                acc[g][c] = fmaf(yv, w[c], acc[g][c]);
        }
    }

    #pragma unroll
    for (int g = 0; g < 4; ++g) {
        const int node = tile * 32 + ty4 + g;
        uint4 pkt;
        uint32_t pv[4];
        #pragma unroll
        for (int p = 0; p < 4; ++p) {
            float vA = acc[g][2 * p]     + (vhalf ? b1sh[cc + 2 * p]     : 0.f);
            float vB = acc[g][2 * p + 1] + (vhalf ? b1sh[cc + 2 * p + 1] : 0.f);
            pv[p] = (uint32_t)f2bf(vA) | ((uint32_t)f2bf(vB) << 16);
        }
        pkt.x = pv[0]; pkt.y = pv[1]; pkt.z = pv[2]; pkt.w = pv[3];
        *(uint4*)&UV[node * 256 + c0] = pkt;
    }
}

// ---------- kernel 2: softmax + weighted relu-sum + GEMV(W2) ----------
// block = 256 thr = 4 waves; each wave handles 8 nodes; block = 32 nodes
__global__ __launch_bounds__(256) void k_agg(
    const float* __restrict__ y, const int* __restrict__ idx,
    const unsigned short* __restrict__ UV,
    const float* __restrict__ W2, const float* __restrict__ b2,
    float* __restrict__ out)
{
    __shared__ float w2s[128 * 64];     // W2 row-major (32 KB)
    __shared__ float b2s[64];
    __shared__ float accs[4][8][128];   // per-wave node accumulators

    const int t = threadIdx.x;
    // stage W2
    {
        const float4* src = (const float4*)W2;
        float4* dst = (float4*)w2s;
        #pragma unroll
        for (int i = 0; i < 8; ++i) dst[t + i * 256] = src[t + i * 256];
    }
    if (t < 64) b2s[t] = b2[t];
    __syncthreads();

    const int wave = t >> 6;
    const int lane = t & 63;
    const int nodeBase = blockIdx.x * 32 + wave * 8;

    for (int g = 0; g < 8; ++g) {
        const int i = nodeBase + g;
        // ---- edge scores: 16 edges, computed redundantly in each 16-lane group ----
        const int e = lane & 15;
        const int j = idx[i * DEG + e];
        const float2 q  = *(const float2*)&y[i * 64];
        const float2 kv = *(const float2*)&y[(long)j * 64];
        const float nq = fmaxf(sqrtf(q.x * q.x + q.y * q.y), 1e-9f);
        const float nk = fmaxf(sqrtf(kv.x * kv.x + kv.y * kv.y), 1e-9f);
        float s = (q.x * kv.x + q.y * kv.y) / (nq * nk);
        float m = s;
        #pragma unroll
        for (int d = 1; d < 16; d <<= 1) m = fmaxf(m, __shfl_xor(m, d));
        const float ex = __expf(s - m);
        float sum = ex;
        #pragma unroll
        for (int d = 1; d < 16; d <<= 1) sum += __shfl_xor(sum, d);
        const float a = ex / sum;

        // ---- weighted relu accumulation: lane owns cols {2*lane, 2*lane+1} ----
        const uint32_t vraw = *(const uint32_t*)&UV[i * 256 + 128 + 2 * lane];
        const float v0 = bf2f((unsigned short)(vraw & 0xFFFF));
        const float v1 = bf2f((unsigned short)(vraw >> 16));
        float a0 = 0.f, a1 = 0.f;
        #pragma unroll
        for (int ee = 0; ee < 16; ++ee) {
            const float ae = __shfl(a, ee);
            const int   je = __shfl(j, ee);
            const uint32_t u = *(const uint32_t*)&UV[(long)je * 256 + 2 * lane];
            const float u0 = bf2f((unsigned short)(u & 0xFFFF));
            const float u1 = bf2f((unsigned short)(u >> 16));
            a0 = fmaf(ae, fmaxf(u0 + v0, 0.f), a0);
            a1 = fmaf(ae, fmaxf(u1 + v1, 0.f), a1);
        }
        *(float2*)&accs[wave][g][2 * lane] = make_float2(a0, a1);
    }

    // ---- GEMV: out[i] = acc @ W2 + b2 ; lane = output column ----
    float og[8];
    #pragma unroll
    for (int g = 0; g < 8; ++g) og[g] = 0.f;

    const int c = lane;
    for (int k = 0; k < 128; ++k) {
        const float wv = w2s[k * 64 + c];
        #pragma unroll
        for (int g = 0; g < 8; ++g)
            og[g] = fmaf(accs[wave][g][k], wv, og[g]);
    }
    #pragma unroll
    for (int g = 0; g < 8; ++g)
        out[(long)(nodeBase + g) * 64 + c] = og[g] + b2s[c];
}

extern "C" void kernel_launch(void* const* d_in, const int* in_sizes, int n_in,
                              void* d_out, int out_size, void* d_ws, size_t ws_size,
                              hipStream_t stream) {
    const float* y   = (const float*)d_in[0];
    const int*   idx = (const int*)d_in[1];
    // d_in[2] = indptr: uniform DEG=16, unused
    const float* W1  = (const float*)d_in[3];
    const float* b1  = (const float*)d_in[4];
    const float* W2  = (const float*)d_in[5];
    const float* b2  = (const float*)d_in[6];
    float* out = (float*)d_out;
    unsigned short* UV = (unsigned short*)d_ws;  // 100000*256 bf16 = 51.2 MB

    k_uv<<<3125, 256, 0, stream>>>(y, W1, b1, UV);
    k_agg<<<3125, 256, 0, stream>>>(y, idx, UV, W2, b2, out);
}

// Round 2
// 136.881 us; speedup vs baseline: 1.3312x; 1.3312x over previous
//
#include <hip/hip_runtime.h>
#include <hip/hip_bf16.h>
#include <cstdint>

#define DEG 16
#define NNODE 100000
#define NTILE 3125

typedef __attribute__((ext_vector_type(8))) short short8v;
typedef __attribute__((ext_vector_type(4))) float f32x4;

__device__ __forceinline__ float bflo(uint32_t u) {
    union { float f; uint32_t i; } c; c.i = u << 16; return c.f;
}
__device__ __forceinline__ float bfhi(uint32_t u) {
    union { float f; uint32_t i; } c; c.i = u & 0xffff0000u; return c.f;
}
__device__ __forceinline__ unsigned short f2bf(float f) {
    union { float f; uint32_t i; } c; c.f = f;
    uint32_t r = (c.i + 0x7FFFu + ((c.i >> 16) & 1u)) >> 16;
    return (unsigned short)r;
}
__device__ __forceinline__ uint32_t pack2(float a, float b) {
    return (uint32_t)f2bf(a) | ((uint32_t)f2bf(b) << 16);
}

// ---------------- kernel 1: U = y@W1top (bf16), V = y@W1bot + b1 (bf16), QN = normalized coords ----------------
// W1 read directly from global (64 KB, L2-resident for all blocks). LDS = y tile only.
__global__ __launch_bounds__(256) void k_uv(
    const float* __restrict__ y, const float* __restrict__ W1,
    const float* __restrict__ b1,
    unsigned short* __restrict__ Ub, unsigned short* __restrict__ Vb,
    float2* __restrict__ QN)
{
    __shared__ float ysh[32][65];
    const int t = threadIdx.x;
    const int tile = blockIdx.x;
    const int base = tile * 32 * 64;

    #pragma unroll
    for (int i = 0; i < 8; ++i) {
        const int e = t + i * 256;
        ysh[e >> 6][e & 63] = y[base + e];
    }
    __syncthreads();

    if (QN != nullptr && t < 32) {
        const int node = tile * 32 + t;
        const float qx = ysh[t][0], qy = ysh[t][1];
        const float n = fmaxf(sqrtf(qx * qx + qy * qy), 1e-9f);
        QN[node] = make_float2(qx / n, qy / n);
    }

    const int tx = t & 31;            // 32 column groups of 8 (over 256 combined cols)
    const int ty = t >> 5;            // 8 node groups of 4
    const int c0 = tx * 8;
    const bool vhalf = (c0 >= 128);
    const int cc = vhalf ? (c0 - 128) : c0;   // col within the 128-wide half
    const int rbase = vhalf ? 64 : 0;
    const int ty4 = ty * 4;

    float bA[8];
    #pragma unroll
    for (int p = 0; p < 8; ++p) bA[p] = 0.f;
    if (vhalf) {
        const float4 ba = *(const float4*)&b1[cc];
        const float4 bb = *(const float4*)&b1[cc + 4];
        bA[0]=ba.x; bA[1]=ba.y; bA[2]=ba.z; bA[3]=ba.w;
        bA[4]=bb.x; bA[5]=bb.y; bA[6]=bb.z; bA[7]=bb.w;
    }

    float acc[4][8];
    #pragma unroll
    for (int g = 0; g < 4; ++g)
        #pragma unroll
        for (int c = 0; c < 8; ++c) acc[g][c] = 0.f;

    const float4* W1v = (const float4*)W1;
    const int widx0 = rbase * 32 + (cc >> 2);

    #pragma unroll 4
    for (int k = 0; k < 64; ++k) {
        const float4 wa = W1v[widx0 + k * 32];
        const float4 wb = W1v[widx0 + k * 32 + 1];
        const float w[8] = {wa.x, wa.y, wa.z, wa.w, wb.x, wb.y, wb.z, wb.w};
        #pragma unroll
        for (int g = 0; g < 4; ++g) {
            const float yv = ysh[ty4 + g][k];
            #pragma unroll
            for (int c = 0; c < 8; ++c)
                acc[g][c] = fmaf(yv, w[c], acc[g][c]);
        }
    }

    unsigned short* dst = vhalf ? Vb : Ub;
    #pragma unroll
    for (int g = 0; g < 4; ++g) {
        const int node = tile * 32 + ty4 + g;
        uint4 pkt;
        pkt.x = pack2(acc[g][0] + bA[0], acc[g][1] + bA[1]);
        pkt.y = pack2(acc[g][2] + bA[2], acc[g][3] + bA[3]);
        pkt.z = pack2(acc[g][4] + bA[4], acc[g][5] + bA[5]);
        pkt.w = pack2(acc[g][6] + bA[6], acc[g][7] + bA[7]);
        *(uint4*)&dst[(long)node * 128 + cc] = pkt;
    }
}

// ---------------- kernel 2: softmax + weighted relu-sum + MFMA GEMV ----------------
// block = 256 = 4 waves; wave handles 8 nodes' edge phase; block-wide MFMA epilogue.
template<bool USE_QN>
__global__ __launch_bounds__(256, 6) void k_agg(
    const float* __restrict__ y, const int* __restrict__ idx,
    const unsigned short* __restrict__ Ub, const unsigned short* __restrict__ Vb,
    const float2* __restrict__ QN,
    const float* __restrict__ W2, const float* __restrict__ b2,
    float* __restrict__ out)
{
    __shared__ unsigned short w2t[64 * 128];   // W2^T bf16, swizzled: 16 KB
    __shared__ uint32_t accs[32 * 64];         // 32 nodes x 128 cols bf16, swizzled: 8 KB

    const int t = threadIdx.x;
    const int lane = t & 63;
    const int wave = t >> 6;

    // ---- stage W2^T (bf16, XOR-swizzled rows) ----
    {
        const int c = t & 63;
        const int k0 = t >> 6;
        char* wbp = (char*)w2t;
        const int sw = (c & 7) << 4;
        #pragma unroll
        for (int i = 0; i < 32; ++i) {
            const int k = k0 + i * 4;
            const unsigned short v = f2bf(W2[k * 64 + c]);
            *(unsigned short*)(wbp + ((c * 256 + k * 2) ^ sw)) = v;
        }
    }

    const int nodeBase = blockIdx.x * 32 + wave * 8;
    const int e = lane & 15;
    const int c32 = lane & 31;
    const int half = lane >> 5;

    // ---- hoist idx loads ----
    int jA[8];
    #pragma unroll
    for (int g = 0; g < 8; ++g)
        jA[g] = idx[(nodeBase + g) * DEG + e];

    // ---- softmax phase (16-lane groups, replicated x4) ----
    float aA[8];
    #pragma unroll
    for (int g = 0; g < 8; ++g) {
        const int i = nodeBase + g;
        float s;
        if (USE_QN) {
            const float2 qn = QN[i];
            const float2 kn = QN[jA[g]];
            s = qn.x * kn.x + qn.y * kn.y;
        } else {
            const float2 q  = *(const float2*)&y[(long)i * 64];
            const float2 kv = *(const float2*)&y[(long)jA[g] * 64];
            const float nq = fmaxf(sqrtf(q.x * q.x + q.y * q.y), 1e-9f);
            const float nk = fmaxf(sqrtf(kv.x * kv.x + kv.y * kv.y), 1e-9f);
            s = (q.x * kv.x + q.y * kv.y) / (nq * nk);
        }
        float m = s;
        #pragma unroll
        for (int d = 1; d < 16; d <<= 1) m = fmaxf(m, __shfl_xor(m, d));
        const float ex = __expf(s - m);
        float sum = ex;
        #pragma unroll
        for (int d = 1; d < 16; d <<= 1) sum += __shfl_xor(sum, d);
        aA[g] = ex / sum;
    }

    // ---- gather/accumulate phase: 2 edges per iter (half-wave each, uint2/lane) ----
    const uint2* Uv = (const uint2*)Ub;
    const uint2* Vv = (const uint2*)Vb;
    char* accb = (char*)accs;

    #pragma unroll 1
    for (int g = 0; g < 8; ++g) {
        const int i = nodeBase + g;
        const uint2 vr = Vv[(long)i * 32 + c32];
        const float v0 = bflo(vr.x), v1 = bfhi(vr.x);
        const float v2 = bflo(vr.y), v3 = bfhi(vr.y);
        float a0 = 0.f, a1 = 0.f, a2 = 0.f, a3 = 0.f;
        #pragma unroll
        for (int ee = 0; ee < 8; ++ee) {
            const int src = 2 * ee + half;
            const float ae = __shfl(aA[g], src);
            const int   je = __shfl(jA[g], src);
            const uint2 u = Uv[(long)je * 32 + c32];
            a0 = fmaf(ae, fmaxf(bflo(u.x) + v0, 0.f), a0);
            a1 = fmaf(ae, fmaxf(bfhi(u.x) + v1, 0.f), a1);
            a2 = fmaf(ae, fmaxf(bflo(u.y) + v2, 0.f), a2);
            a3 = fmaf(ae, fmaxf(bfhi(u.y) + v3, 0.f), a3);
        }
        // combine the two half-wave partials
        a0 += __shfl_xor(a0, 32);
        a1 += __shfl_xor(a1, 32);
        a2 += __shfl_xor(a2, 32);
        a3 += __shfl_xor(a3, 32);
        if (half == 0) {
            const int r = wave * 8 + g;
            uint2 pk;
            pk.x = pack2(a0, a1);
            pk.y = pack2(a2, a3);
            *(uint2*)(accb + ((r * 256 + 8 * c32) ^ ((r & 7) << 4))) = pk;
        }
    }
    __syncthreads();

    // ---- MFMA GEMV: C[32x64] = ACC[32x128] @ W2[128x64] ----
    // wave w: tm = w>>1 (16-row group), tn = 2*(w&1) + {0,1} (16-col groups)
    const int lo = lane & 15, hi = lane >> 4;
    const int tm = wave >> 1;
    const int tn0 = (wave & 1) * 2;
    const int r = 16 * tm + lo;
    const int rsw = (r & 7) << 4;

    short8v afr[4];
    #pragma unroll
    for (int kb = 0; kb < 4; ++kb)
        afr[kb] = *(const short8v*)(accb + ((r * 256 + kb * 64 + hi * 16) ^ rsw));

    const int cB0 = 16 * tn0 + lo;
    const int cB1 = cB0 + 16;
    const int sw0 = (cB0 & 7) << 4;
    const int sw1 = (cB1 & 7) << 4;
    char* w2b = (char*)w2t;

    f32x4 d0 = {0.f, 0.f, 0.f, 0.f};
    f32x4 d1 = {0.f, 0.f, 0.f, 0.f};
    #pragma unroll
    for (int kb = 0; kb < 4; ++kb) {
        const short8v bf0 = *(const short8v*)(w2b + ((cB0 * 256 + kb * 64 + hi * 16) ^ sw0));
        const short8v bf1 = *(const short8v*)(w2b + ((cB1 * 256 + kb * 64 + hi * 16) ^ sw1));
        d0 = __builtin_amdgcn_mfma_f32_16x16x32_bf16(afr[kb], bf0, d0, 0, 0, 0);
        d1 = __builtin_amdgcn_mfma_f32_16x16x32_bf16(afr[kb], bf1, d1, 0, 0, 0);
    }

    const float bb0 = b2[cB0];
    const float bb1 = b2[cB1];
    const long rowBase = (long)(blockIdx.x * 32 + 16 * tm);
    #pragma unroll
    for (int p = 0; p < 4; ++p) {
        const long row = rowBase + hi * 4 + p;
        out[row * 64 + cB0] = d0[p] + bb0;
        out[row * 64 + cB1] = d1[p] + bb1;
    }
}

extern "C" void kernel_launch(void* const* d_in, const int* in_sizes, int n_in,
                              void* d_out, int out_size, void* d_ws, size_t ws_size,
                              hipStream_t stream) {
    const float* y   = (const float*)d_in[0];
    const int*   idx = (const int*)d_in[1];
    // d_in[2] = indptr: uniform DEG=16, unused
    const float* W1  = (const float*)d_in[3];
    const float* b1  = (const float*)d_in[4];
    const float* W2  = (const float*)d_in[5];
    const float* b2  = (const float*)d_in[6];
    float* out = (float*)d_out;

    unsigned short* Ub = (unsigned short*)d_ws;                  // 25.6 MB
    unsigned short* Vb = Ub + (size_t)NNODE * 128;               // 25.6 MB
    const size_t qn_off = (size_t)NNODE * 128 * 2 * 2;           // 51.2 MB
    const bool useQN = (ws_size >= qn_off + (size_t)NNODE * sizeof(float2));
    float2* QN = useQN ? (float2*)((char*)d_ws + qn_off) : nullptr;

    k_uv<<<NTILE, 256, 0, stream>>>(y, W1, b1, Ub, Vb, QN);
    if (useQN)
        k_agg<true><<<NTILE, 256, 0, stream>>>(y, idx, Ub, Vb, QN, W2, b2, out);
    else
        k_agg<false><<<NTILE, 256, 0, stream>>>(y, idx, Ub, Vb, nullptr, W2, b2, out);
}

// Round 5
// 106.921 us; speedup vs baseline: 1.7042x; 1.2802x over previous
//
#include <hip/hip_runtime.h>
#include <cstdint>

#define DEG 16
#define NNODE 100000
#define NTILE 3125

typedef _Float16 f16;
typedef _Float16 h2v  __attribute__((ext_vector_type(2)));
typedef _Float16 f16x8 __attribute__((ext_vector_type(8)));
typedef float    f32x4 __attribute__((ext_vector_type(4)));

union U4 { uint4 u; h2v h[4]; f16x8 v; };
union U2 { uint2 u; h2v h[2]; };
union U1 { uint32_t i; h2v h; };

__device__ __forceinline__ h2v pk2h(float a, float b) {
    auto r = __builtin_amdgcn_cvt_pkrtz(a, b);   // __fp16 ext_vector(2)
    h2v o;
    __builtin_memcpy(&o, &r, sizeof(o));
    return o;
}

// ---------------- k_prep: lay out combined [W1top; W1bot]^T and W2^T as MFMA A-fragments (f16) ----------------
// W1A[mt(16)][kb(2)][lane(64)][j(8)] : element Acomb[m][k], m=16*mt+(lane&15), k=kb*32+(lane>>4)*8+j
//   Acomb[m][k] = (m<128) ? W1[k][m] : W1[64+k][m-128]
// W2A[mt(4)][kb(4)][lane(64)][j(8)]  : element W2[k][c], c=16*mt+(lane&15), k=kb*32+(lane>>4)*8+j
__global__ __launch_bounds__(256) void k_prep(
    const float* __restrict__ W1, const float* __restrict__ W2,
    f16* __restrict__ W1A, f16* __restrict__ W2A)
{
    const int g0 = blockIdx.x * 256 + threadIdx.x;
    for (int i = g0; i < 16384 + 8192; i += 24 * 256) {
        if (i < 16384) {
            const int j = i & 7, lane = (i >> 3) & 63, kb = (i >> 9) & 1, mt = i >> 10;
            const int m = 16 * mt + (lane & 15);
            const int k = kb * 32 + (lane >> 4) * 8 + j;
            const int row = (m < 128) ? k : (64 + k);
            const int col = m & 127;
            W1A[i] = (f16)W1[row * 128 + col];
        } else {
            const int ii = i - 16384;
            const int j = ii & 7, lane = (ii >> 3) & 63, kb = (ii >> 9) & 3, mt = ii >> 11;
            const int c = 16 * mt + (lane & 15);
            const int k = kb * 32 + (lane >> 4) * 8 + j;
            W2A[ii] = (f16)W2[k * 64 + c];
        }
    }
}

// ---------------- k_uv: swapped-operand MFMA GEMM  D[256 cols][32 nodes] = Acomb x y^T ----------------
// Output per node row-major f16 into Uh (cols 0..127) / Vh (+b1, cols 128..255). No LDS.
__global__ __launch_bounds__(256, 4) void k_uv(
    const float* __restrict__ y, const f16* __restrict__ W1A,
    const float* __restrict__ b1,
    f16* __restrict__ Uh, f16* __restrict__ Vh, float2* __restrict__ QN)
{
    const int t = threadIdx.x;
    const int tile = blockIdx.x;
    const int lane = t & 63;
    const int w = t >> 6;

    if (QN != nullptr && t < 32) {
        const int node = tile * 32 + t;
        const float qx = y[node * 64], qy = y[node * 64 + 1];
        const float n = fmaxf(sqrtf(qx * qx + qy * qy), 1e-9f);
        QN[node] = make_float2(qx / n, qy / n);
    }

    // B-fragments from y (col = node, k = feature)
    f16x8 bf[2][2];
    #pragma unroll
    for (int nt = 0; nt < 2; ++nt) {
        const long node = tile * 32 + 16 * nt + (lane & 15);
        #pragma unroll
        for (int kb = 0; kb < 2; ++kb) {
            const int k0 = kb * 32 + (lane >> 4) * 8;
            const float4 a = *(const float4*)&y[node * 64 + k0];
            const float4 b = *(const float4*)&y[node * 64 + k0 + 4];
            U4 r;
            r.h[0] = pk2h(a.x, a.y);
            r.h[1] = pk2h(a.z, a.w);
            r.h[2] = pk2h(b.x, b.y);
            r.h[3] = pk2h(b.z, b.w);
            bf[nt][kb] = r.v;
        }
    }

    f32x4 acc[4][2];
    #pragma unroll
    for (int i = 0; i < 4; ++i)
        #pragma unroll
        for (int nt = 0; nt < 2; ++nt)
            acc[i][nt] = (f32x4){0.f, 0.f, 0.f, 0.f};

    #pragma unroll
    for (int i = 0; i < 4; ++i) {
        const int mt = 4 * w + i;
        #pragma unroll
        for (int kb = 0; kb < 2; ++kb) {
            const f16x8 af = *(const f16x8*)&W1A[((mt * 2 + kb) * 64 + lane) * 8];
            #pragma unroll
            for (int nt = 0; nt < 2; ++nt)
                acc[i][nt] = __builtin_amdgcn_mfma_f32_16x16x32_f16(af, bf[nt][kb], acc[i][nt], 0, 0, 0);
        }
    }

    // epilogue: lane holds node = 16nt+(lane&15), cols cc0..cc0+3
    #pragma unroll
    for (int i = 0; i < 4; ++i) {
        const int mt = 4 * w + i;
        const int cc0 = 16 * mt + (lane >> 4) * 4;
        float4 badd = {0.f, 0.f, 0.f, 0.f};
        if (w >= 2) badd = *(const float4*)&b1[cc0 - 128];
        #pragma unroll
        for (int nt = 0; nt < 2; ++nt) {
            const long node = tile * 32 + 16 * nt + (lane & 15);
            U2 pk;
            pk.h[0] = pk2h(acc[i][nt][0] + badd.x, acc[i][nt][1] + badd.y);
            pk.h[1] = pk2h(acc[i][nt][2] + badd.z, acc[i][nt][3] + badd.w);
            if (w < 2) *(uint2*)&Uh[node * 128 + cc0]         = pk.u;
            else       *(uint2*)&Vh[node * 128 + (cc0 - 128)] = pk.u;
        }
    }
}

// ---------------- k_agg: softmax + packed-f16 weighted relu-sum + swapped MFMA epilogue ----------------
template<bool USE_QN>
__global__ __launch_bounds__(256, 6) void k_agg(
    const float* __restrict__ y, const int* __restrict__ idx,
    const f16* __restrict__ Uh, const f16* __restrict__ Vh,
    const float2* __restrict__ QN, const f16* __restrict__ W2A,
    const float* __restrict__ b2, float* __restrict__ out)
{
    __shared__ uint32_t accs[2048];   // 32 rows x 128 f16 (256 B), XOR-swizzled

    const int t = threadIdx.x, lane = t & 63, wave = t >> 6;
    const int c16 = lane & 15, quarter = lane >> 4;
    const int nodeBase = blockIdx.x * 32 + wave * 8;

    // early: W2 A-fragments + b2 (needed only in epilogue; hides latency)
    f16x8 waf[4];
    #pragma unroll
    for (int kb = 0; kb < 4; ++kb)
        waf[kb] = *(const f16x8*)&W2A[((wave * 4 + kb) * 64 + lane) * 8];
    const float4 b2v = *(const float4*)&b2[16 * wave + quarter * 4];

    int jA[8]; float aA[8];
    #pragma unroll
    for (int g = 0; g < 8; ++g)
        jA[g] = idx[(nodeBase + g) * DEG + c16];

    // ---- scores + segment softmax (16-lane groups, replicated across quarters) ----
    #pragma unroll
    for (int g = 0; g < 8; ++g) {
        const int i = nodeBase + g;
        float s;
        if (USE_QN) {
            const float2 qn = QN[i];
            const float2 kn = QN[jA[g]];
            s = qn.x * kn.x + qn.y * kn.y;
        } else {
            const float2 q  = *(const float2*)&y[(long)i * 64];
            const float2 kv = *(const float2*)&y[(long)jA[g] * 64];
            const float nq = fmaxf(sqrtf(q.x * q.x + q.y * q.y), 1e-9f);
            const float nk = fmaxf(sqrtf(kv.x * kv.x + kv.y * kv.y), 1e-9f);
            s = (q.x * kv.x + q.y * kv.y) / (nq * nk);
        }
        float m = s;
        #pragma unroll
        for (int d = 1; d < 16; d <<= 1) m = fmaxf(m, __shfl_xor(m, d));
        const float ex = __expf(s - m);
        float sum = ex;
        #pragma unroll
        for (int d = 1; d < 16; d <<= 1) sum += __shfl_xor(sum, d);
        aA[g] = ex / sum;
    }

    // ---- gather/accumulate: 4 edges per iter (quarter-waves, uint4 = 8 cols/lane) ----
    char* accb = (char*)accs;
    #pragma unroll 2
    for (int g = 0; g < 8; ++g) {
        const long i = nodeBase + g;
        U4 vfr; vfr.u = *((const uint4*)(Vh + i * 128) + c16);
        h2v r0 = {0, 0}, r1 = {0, 0}, r2 = {0, 0}, r3 = {0, 0};
        const h2v z2 = {0, 0};
        #pragma unroll
        for (int ee = 0; ee < 4; ++ee) {
            const int srcl = 4 * ee + quarter;
            const float ae = __shfl(aA[g], srcl);
            const long  je = __shfl(jA[g], srcl);
            U4 u; u.u = *((const uint4*)(Uh + je * 128) + c16);
            const h2v az = pk2h(ae, ae);
            h2v s0 = __builtin_elementwise_max(u.h[0] + vfr.h[0], z2);
            h2v s1 = __builtin_elementwise_max(u.h[1] + vfr.h[1], z2);
            h2v s2 = __builtin_elementwise_max(u.h[2] + vfr.h[2], z2);
            h2v s3 = __builtin_elementwise_max(u.h[3] + vfr.h[3], z2);
            r0 += s0 * az; r1 += s1 * az; r2 += s2 * az; r3 += s3 * az;
        }
        // reduce across the 4 quarter-groups
        h2v rr[4] = {r0, r1, r2, r3};
        #pragma unroll
        for (int p = 0; p < 4; ++p) {
            U1 v; v.h = rr[p];
            U1 o; o.i = __shfl_xor(v.i, 16); v.h = v.h + o.h;
            o.i = __shfl_xor(v.i, 32);       v.h = v.h + o.h;
            rr[p] = v.h;
        }
        if (quarter == 0) {
            const int rrow = wave * 8 + g;
            U4 pk; pk.h[0] = rr[0]; pk.h[1] = rr[1]; pk.h[2] = rr[2]; pk.h[3] = rr[3];
            *(uint4*)(accb + ((rrow * 256 + c16 * 16) ^ ((rrow & 7) << 4))) = pk.u;
        }
    }
    __syncthreads();

    // ---- swapped MFMA epilogue: D[64 W2cols][32 nodes] = W2^T x ACC^T ----
    f32x4 d[2];
    #pragma unroll
    for (int nt = 0; nt < 2; ++nt) d[nt] = (f32x4){0.f, 0.f, 0.f, 0.f};
    #pragma unroll
    for (int nt = 0; nt < 2; ++nt) {
        const int n = 16 * nt + c16;
        const int sw = (n & 7) << 4;
        #pragma unroll
        for (int kb = 0; kb < 4; ++kb) {
            const f16x8 bfr = *(const f16x8*)(accb + ((n * 256 + kb * 64 + quarter * 16) ^ sw));
            d[nt] = __builtin_amdgcn_mfma_f32_16x16x32_f16(waf[kb], bfr, d[nt], 0, 0, 0);
        }
    }
    #pragma unroll
    for (int nt = 0; nt < 2; ++nt) {
        const long node = blockIdx.x * 32 + 16 * nt + c16;
        const int col = 16 * wave + quarter * 4;
        float4 o;
        o.x = d[nt][0] + b2v.x; o.y = d[nt][1] + b2v.y;
        o.z = d[nt][2] + b2v.z; o.w = d[nt][3] + b2v.w;
        *(float4*)&out[node * 64 + col] = o;
    }
}

extern "C" void kernel_launch(void* const* d_in, const int* in_sizes, int n_in,
                              void* d_out, int out_size, void* d_ws, size_t ws_size,
                              hipStream_t stream) {
    const float* y   = (const float*)d_in[0];
    const int*   idx = (const int*)d_in[1];
    // d_in[2] = indptr: uniform DEG=16, unused
    const float* W1  = (const float*)d_in[3];
    const float* b1  = (const float*)d_in[4];
    const float* W2  = (const float*)d_in[5];
    const float* b2  = (const float*)d_in[6];
    float* out = (float*)d_out;

    char* ws = (char*)d_ws;
    f16* Uh  = (f16*)ws;                                   // 25,600,000 B
    f16* Vh  = (f16*)(ws + 25600000);                      // 25,600,000 B
    f16* W1A = (f16*)(ws + 51200000);                      // 32,768 B
    f16* W2A = (f16*)(ws + 51232768);                      // 16,384 B
    const size_t qn_off = 51249152;
    const bool useQN = (ws_size >= qn_off + (size_t)NNODE * sizeof(float2));
    float2* QN = useQN ? (float2*)(ws + qn_off) : nullptr;

    k_prep<<<24, 256, 0, stream>>>(W1, W2, W1A, W2A);
    k_uv<<<NTILE, 256, 0, stream>>>(y, W1A, b1, Uh, Vh, QN);
    if (useQN)
        k_agg<true><<<NTILE, 256, 0, stream>>>(y, idx, Uh, Vh, QN, W2A, b2, out);
    else
        k_agg<false><<<NTILE, 256, 0, stream>>>(y, idx, Uh, Vh, nullptr, W2A, b2, out);
}

// Round 6
// 98.035 us; speedup vs baseline: 1.8586x; 1.0906x over previous
//
#include <hip/hip_runtime.h>
#include <cstdint>

#define DEG 16
#define NNODE 100000
#define NTILE 3125

typedef _Float16 f16;
typedef _Float16 h2v  __attribute__((ext_vector_type(2)));
typedef _Float16 f16x8 __attribute__((ext_vector_type(8)));
typedef float    f32x4 __attribute__((ext_vector_type(4)));

union U4 { uint4 u; h2v h[4]; f16x8 v; };
union U2 { uint2 u; h2v h[2]; };
union U1 { uint32_t i; h2v h; };

__device__ __forceinline__ h2v pk2h(float a, float b) {
    auto r = __builtin_amdgcn_cvt_pkrtz(a, b);   // __fp16 ext_vector(2)
    h2v o;
    __builtin_memcpy(&o, &r, sizeof(o));
    return o;
}

// K-permutation (involution): swap bit-fields [2:3] and [4:5] of a 0..127 index.
__device__ __host__ __forceinline__ int kperm(int p) {
    return (p & 0xC3) | ((p & 0x0C) << 2) | ((p & 0x30) >> 2);
}

// ---------------- k_prep ----------------
// W1A[mt(16)][kb(2)][lane(64)][j(8)] : element Acomb[m][k], m=16*mt+(lane&15), k=kb*32+(lane>>4)*8+j
//   Acomb[m][k] = (m<128) ? W1[k][m] : W1[64+k][m-128]      (k = y-feature dim, NOT permuted)
// W2A[mt(4)][kb(4)][lane(64)][j(8)]  : element W2[kperm(p)][c], p=kb*32+(lane>>4)*8+j, c=16*mt+(lane&15)
//   (K dim permuted to match the permuted U/V storage layout)
__global__ __launch_bounds__(256) void k_prep(
    const float* __restrict__ W1, const float* __restrict__ W2,
    f16* __restrict__ W1A, f16* __restrict__ W2A)
{
    const int g0 = blockIdx.x * 256 + threadIdx.x;
    for (int i = g0; i < 16384 + 8192; i += 24 * 256) {
        if (i < 16384) {
            const int j = i & 7, lane = (i >> 3) & 63, kb = (i >> 9) & 1, mt = i >> 10;
            const int m = 16 * mt + (lane & 15);
            const int k = kb * 32 + (lane >> 4) * 8 + j;
            const int row = (m < 128) ? k : (64 + k);
            const int col = m & 127;
            W1A[i] = (f16)W1[row * 128 + col];
        } else {
            const int ii = i - 16384;
            const int j = ii & 7, lane = (ii >> 3) & 63, kb = (ii >> 9) & 3, mt = ii >> 11;
            const int c = 16 * mt + (lane & 15);
            const int p = kb * 32 + (lane >> 4) * 8 + j;
            W2A[ii] = (f16)W2[kperm(p) * 64 + c];
        }
    }
}

// ---------------- k_uv: swapped-operand MFMA GEMM  D[256 cols][32 nodes] = Acomb x y^T ----------------
// Stores U/V rows in PERMUTED layout: position p = 64*(w&1) + 16*q + 4*i + r holds true col 64*(w&1)+16*i+4*q+r.
// Each lane owns 16 contiguous f16 -> two 16 B stores.
__global__ __launch_bounds__(256, 4) void k_uv(
    const float* __restrict__ y, const f16* __restrict__ W1A,
    const float* __restrict__ b1,
    f16* __restrict__ Uh, f16* __restrict__ Vh, float2* __restrict__ QN)
{
    const int t = threadIdx.x;
    const int tile = blockIdx.x;
    const int lane = t & 63;
    const int w = t >> 6;
    const int c16 = lane & 15, q = lane >> 4;

    if (QN != nullptr && t < 32) {
        const int node = tile * 32 + t;
        const float qx = y[node * 64], qy = y[node * 64 + 1];
        const float n = fmaxf(sqrtf(qx * qx + qy * qy), 1e-9f);
        QN[node] = make_float2(qx / n, qy / n);
    }

    // B-fragments from y (col = node, k = feature)
    f16x8 bf[2][2];
    #pragma unroll
    for (int nt = 0; nt < 2; ++nt) {
        const long node = tile * 32 + 16 * nt + c16;
        #pragma unroll
        for (int kb = 0; kb < 2; ++kb) {
            const int k0 = kb * 32 + q * 8;
            const float4 a = *(const float4*)&y[node * 64 + k0];
            const float4 b = *(const float4*)&y[node * 64 + k0 + 4];
            U4 r;
            r.h[0] = pk2h(a.x, a.y);
            r.h[1] = pk2h(a.z, a.w);
            r.h[2] = pk2h(b.x, b.y);
            r.h[3] = pk2h(b.z, b.w);
            bf[nt][kb] = r.v;
        }
    }

    f32x4 acc[4][2];
    #pragma unroll
    for (int i = 0; i < 4; ++i)
        #pragma unroll
        for (int nt = 0; nt < 2; ++nt)
            acc[i][nt] = (f32x4){0.f, 0.f, 0.f, 0.f};

    #pragma unroll
    for (int i = 0; i < 4; ++i) {
        const int mt = 4 * w + i;
        #pragma unroll
        for (int kb = 0; kb < 2; ++kb) {
            const f16x8 af = *(const f16x8*)&W1A[((mt * 2 + kb) * 64 + lane) * 8];
            #pragma unroll
            for (int nt = 0; nt < 2; ++nt)
                acc[i][nt] = __builtin_amdgcn_mfma_f32_16x16x32_f16(af, bf[nt][kb], acc[i][nt], 0, 0, 0);
        }
    }

    // epilogue: lane (w,q,c16) holds, for each nt, true cols {16*(4w+i)+4q+r}.
    // Store to permuted positions 64*(w&1)+16*q+4*i+r : 16 contiguous f16 per (lane,nt).
    const bool isV = (w >= 2);
    const int wef = w & 1;
    float4 b1v[4];
    #pragma unroll
    for (int i = 0; i < 4; ++i) b1v[i] = make_float4(0.f, 0.f, 0.f, 0.f);
    if (isV) {
        #pragma unroll
        for (int i = 0; i < 4; ++i)
            b1v[i] = *(const float4*)&b1[wef * 64 + 16 * i + 4 * q];
    }

    f16* const dstBase = isV ? Vh : Uh;
    #pragma unroll
    for (int nt = 0; nt < 2; ++nt) {
        const long node = tile * 32 + 16 * nt + c16;
        f16* dst = dstBase + node * 128 + wef * 64 + q * 16;
        U4 p0, p1;
        p0.h[0] = pk2h(acc[0][nt][0] + b1v[0].x, acc[0][nt][1] + b1v[0].y);
        p0.h[1] = pk2h(acc[0][nt][2] + b1v[0].z, acc[0][nt][3] + b1v[0].w);
        p0.h[2] = pk2h(acc[1][nt][0] + b1v[1].x, acc[1][nt][1] + b1v[1].y);
        p0.h[3] = pk2h(acc[1][nt][2] + b1v[1].z, acc[1][nt][3] + b1v[1].w);
        p1.h[0] = pk2h(acc[2][nt][0] + b1v[2].x, acc[2][nt][1] + b1v[2].y);
        p1.h[1] = pk2h(acc[2][nt][2] + b1v[2].z, acc[2][nt][3] + b1v[2].w);
        p1.h[2] = pk2h(acc[3][nt][0] + b1v[3].x, acc[3][nt][1] + b1v[3].y);
        p1.h[3] = pk2h(acc[3][nt][2] + b1v[3].z, acc[3][nt][3] + b1v[3].w);
        *(uint4*)dst       = p0.u;
        *(uint4*)(dst + 8) = p1.u;
    }
}

// ---------------- k_agg: softmax + double-buffered gather + swapped MFMA epilogue ----------------
template<bool USE_QN>
__global__ __launch_bounds__(256, 4) void k_agg(
    const float* __restrict__ y, const int* __restrict__ idx,
    const f16* __restrict__ Uh, const f16* __restrict__ Vh,
    const float2* __restrict__ QN, const f16* __restrict__ W2A,
    const float* __restrict__ b2, float* __restrict__ out)
{
    __shared__ uint32_t accs[2048];   // 32 rows x 128 f16 (256 B), XOR-swizzled

    const int t = threadIdx.x, lane = t & 63, wave = t >> 6;
    const int c16 = lane & 15, quarter = lane >> 4;
    const int nodeBase = blockIdx.x * 32 + wave * 8;

    int jA[8]; float aA[8];
    #pragma unroll
    for (int g = 0; g < 8; ++g)
        jA[g] = idx[(nodeBase + g) * DEG + c16];

    // ---- scores + segment softmax (16-lane groups, replicated across quarters) ----
    #pragma unroll
    for (int g = 0; g < 8; ++g) {
        const int i = nodeBase + g;
        float s;
        if (USE_QN) {
            const float2 qn = QN[i];
            const float2 kn = QN[jA[g]];
            s = qn.x * kn.x + qn.y * kn.y;
        } else {
            const float2 qv = *(const float2*)&y[(long)i * 64];
            const float2 kv = *(const float2*)&y[(long)jA[g] * 64];
            const float nq = fmaxf(sqrtf(qv.x * qv.x + qv.y * qv.y), 1e-9f);
            const float nk = fmaxf(sqrtf(kv.x * kv.x + kv.y * kv.y), 1e-9f);
            s = (qv.x * kv.x + qv.y * kv.y) / (nq * nk);
        }
        float m = s;
        #pragma unroll
        for (int d = 1; d < 16; d <<= 1) m = fmaxf(m, __shfl_xor(m, d));
        const float ex = __expf(s - m);
        float sum = ex;
        #pragma unroll
        for (int d = 1; d < 16; d <<= 1) sum += __shfl_xor(sum, d);
        aA[g] = ex / sum;
    }

    // ---- gather/accumulate: node-level double buffer (V row + 4 U rows in flight) ----
    const uint4* Uv = (const uint4*)Uh;
    const uint4* Vv = (const uint4*)Vh;
    char* accb = (char*)accs;

    U4 ub[2][4], vb[2];
    vb[0].u = Vv[(long)nodeBase * 16 + c16];
    #pragma unroll
    for (int ee = 0; ee < 4; ++ee) {
        const long je = __shfl(jA[0], 4 * ee + quarter);
        ub[0][ee].u = Uv[je * 16 + c16];
    }

    #pragma unroll
    for (int g = 0; g < 8; ++g) {
        const int cur = g & 1, nx = cur ^ 1;
        if (g < 7) {
            vb[nx].u = Vv[(long)(nodeBase + g + 1) * 16 + c16];
            #pragma unroll
            for (int ee = 0; ee < 4; ++ee) {
                const long je = __shfl(jA[g + 1], 4 * ee + quarter);
                ub[nx][ee].u = Uv[je * 16 + c16];
            }
        }
        const h2v z2 = {0, 0};
        h2v r0 = {0, 0}, r1 = {0, 0}, r2 = {0, 0}, r3 = {0, 0};
        #pragma unroll
        for (int ee = 0; ee < 4; ++ee) {
            const float ae = __shfl(aA[g], 4 * ee + quarter);
            const h2v az = pk2h(ae, ae);
            r0 += __builtin_elementwise_max(ub[cur][ee].h[0] + vb[cur].h[0], z2) * az;
            r1 += __builtin_elementwise_max(ub[cur][ee].h[1] + vb[cur].h[1], z2) * az;
            r2 += __builtin_elementwise_max(ub[cur][ee].h[2] + vb[cur].h[2], z2) * az;
            r3 += __builtin_elementwise_max(ub[cur][ee].h[3] + vb[cur].h[3], z2) * az;
        }
        // reduce across the 4 quarter-groups
        h2v rr[4] = {r0, r1, r2, r3};
        #pragma unroll
        for (int p = 0; p < 4; ++p) {
            U1 v; v.h = rr[p];
            U1 o; o.i = __shfl_xor(v.i, 16); v.h = v.h + o.h;
            o.i = __shfl_xor(v.i, 32);       v.h = v.h + o.h;
            rr[p] = v.h;
        }
        if (quarter == 0) {
            const int rrow = wave * 8 + g;
            U4 pk; pk.h[0] = rr[0]; pk.h[1] = rr[1]; pk.h[2] = rr[2]; pk.h[3] = rr[3];
            *(uint4*)(accb + ((rrow * 256 + c16 * 16) ^ ((rrow & 7) << 4))) = pk.u;
        }
    }
    __syncthreads();

    // ---- swapped MFMA epilogue: D[64 W2cols][32 nodes] = W2'^T x ACC^T (both K-permuted) ----
    f16x8 waf[4];
    #pragma unroll
    for (int kb = 0; kb < 4; ++kb)
        waf[kb] = *(const f16x8*)&W2A[((wave * 4 + kb) * 64 + lane) * 8];
    const float4 b2v = *(const float4*)&b2[16 * wave + quarter * 4];

    f32x4 d[2];
    #pragma unroll
    for (int nt = 0; nt < 2; ++nt) d[nt] = (f32x4){0.f, 0.f, 0.f, 0.f};
    #pragma unroll
    for (int nt = 0; nt < 2; ++nt) {
        const int n = 16 * nt + c16;
        const int sw = (n & 7) << 4;
        #pragma unroll
        for (int kb = 0; kb < 4; ++kb) {
            const f16x8 bfr = *(const f16x8*)(accb + ((n * 256 + kb * 64 + quarter * 16) ^ sw));
            d[nt] = __builtin_amdgcn_mfma_f32_16x16x32_f16(waf[kb], bfr, d[nt], 0, 0, 0);
        }
    }
    #pragma unroll
    for (int nt = 0; nt < 2; ++nt) {
        const long node = blockIdx.x * 32 + 16 * nt + c16;
        const int col = 16 * wave + quarter * 4;
        float4 o;
        o.x = d[nt][0] + b2v.x; o.y = d[nt][1] + b2v.y;
        o.z = d[nt][2] + b2v.z; o.w = d[nt][3] + b2v.w;
        *(float4*)&out[node * 64 + col] = o;
    }
}

extern "C" void kernel_launch(void* const* d_in, const int* in_sizes, int n_in,
                              void* d_out, int out_size, void* d_ws, size_t ws_size,
                              hipStream_t stream) {
    const float* y   = (const float*)d_in[0];
    const int*   idx = (const int*)d_in[1];
    // d_in[2] = indptr: uniform DEG=16, unused
    const float* W1  = (const float*)d_in[3];
    const float* b1  = (const float*)d_in[4];
    const float* W2  = (const float*)d_in[5];
    const float* b2  = (const float*)d_in[6];
    float* out = (float*)d_out;

    char* ws = (char*)d_ws;
    f16* Uh  = (f16*)ws;                                   // 25,600,000 B
    f16* Vh  = (f16*)(ws + 25600000);                      // 25,600,000 B
    f16* W1A = (f16*)(ws + 51200000);                      // 32,768 B
    f16* W2A = (f16*)(ws + 51232768);                      // 16,384 B
    const size_t qn_off = 51249152;
    const bool useQN = (ws_size >= qn_off + (size_t)NNODE * sizeof(float2));
    float2* QN = useQN ? (float2*)(ws + qn_off) : nullptr;

    k_prep<<<24, 256, 0, stream>>>(W1, W2, W1A, W2A);
    k_uv<<<NTILE, 256, 0, stream>>>(y, W1A, b1, Uh, Vh, QN);
    if (useQN)
        k_agg<true><<<NTILE, 256, 0, stream>>>(y, idx, Uh, Vh, QN, W2A, b2, out);
    else
        k_agg<false><<<NTILE, 256, 0, stream>>>(y, idx, Uh, Vh, nullptr, W2A, b2, out);
}